// Round 6
// baseline (293.225 us; speedup 1.0000x reference)
//
#include <hip/hip_runtime.h>
#include <stdint.h>
#include <stddef.h>

typedef int v4i  __attribute__((ext_vector_type(4)));
typedef int v16i __attribute__((ext_vector_type(16)));

#define KCH  512                // K-chunk per LDS buffer
#define PSTR 1040               // LDS pair stride: 2 rows x 512 B + 16 pad
#define BUFB (64 * PSTR)        // 66560 B per buffer
#define LDSB (2 * BUFB)         // 133120 B total

// async global->LDS, 16B per lane. Global addr is per-lane; LDS dest is
// wave-uniform base + lane*16 (contiguous 1024 B per call).
__device__ __forceinline__ void gl_lds16(const uint8_t* g, uint8_t* l) {
    __builtin_amdgcn_global_load_lds(
        (const __attribute__((address_space(1))) uint32_t*)g,
        (__attribute__((address_space(3))) uint32_t*)l,
        16, 0, 0);
}

// Software q8 (float path, used only in the small quant kernels):
// EXACT reference semantics: floor(log2), clamp[-6,8], half-even, sat 448.
__device__ __forceinline__ float q8f(float v) {
    float a = fabsf(v);
    int e = (int)(__float_as_uint(a) >> 23) - 127;
    e = e < -6 ? -6 : (e > 8 ? 8 : e);
    float step  = __uint_as_float((uint32_t)(e - 3 + 127) << 23);  // 2^(e-3)
    float rstep = __uint_as_float((uint32_t)(3 - e + 127) << 23);  // 2^(3-e)
    float q = fminf(rintf(a * rstep) * step, 448.0f);
    return v < 0.0f ? -q : q;
}
__device__ __forceinline__ int qm(float v) {  // q8 value * 512 (exact int)
    return (int)rintf(q8f(v) * 512.0f);
}

// integer round-half-even shift: RNE(a / 2^s), a >= 0, s >= 1
__device__ __forceinline__ uint32_t rne_sh(uint32_t a, int s) {
    uint32_t t = a >> s;
    uint32_t rem = a & ((1u << s) - 1u);
    uint32_t half = 1u << (s - 1);
    t += (rem > half) || (rem == half && (t & 1u));
    return t;
}

__global__ __launch_bounds__(256) void quant_x_kernel(
    const float* __restrict__ in, uint32_t* __restrict__ xh, uint32_t* __restrict__ xl, int n4) {
    int i = blockIdx.x * 256 + threadIdx.x;
    if (i >= n4) return;
    float4 v = ((const float4*)in)[i];
    int m0 = qm(v.x), m1 = qm(v.y), m2 = qm(v.z), m3 = qm(v.w);
    xh[i] = ((uint32_t)((m0 >> 5) & 0xff)) | ((uint32_t)((m1 >> 5) & 0xff) << 8) |
            ((uint32_t)((m2 >> 5) & 0xff) << 16) | ((uint32_t)((m3 >> 5) & 0xff) << 24);
    xl[i] = ((uint32_t)(m0 & 31)) | ((uint32_t)(m1 & 31) << 8) |
            ((uint32_t)(m2 & 31) << 16) | ((uint32_t)(m3 & 31) << 24);
}

__global__ __launch_bounds__(256) void quant_w_kernel(
    const float* __restrict__ in, uint32_t* __restrict__ wm, int n4) {
    int i = blockIdx.x * 256 + threadIdx.x;
    if (i >= n4) return;
    float4 v = ((const float4*)in)[i];
    wm[i] = ((uint32_t)(qm(v.x) & 0xff)) | ((uint32_t)(qm(v.y) & 0xff) << 8) |
            ((uint32_t)(qm(v.z) & 0xff) << 16) | ((uint32_t)(qm(v.w) & 0xff) << 24);
}

// C[M,N] = (32*Ah + Al)[M,K] * Bm[N,K]^T * 2^-18, exact i32 accumulation via
// mfma_i32_32x32x32_i8. 512 threads = 8 waves; block tile 256x128; wave tile
// 32x128 (4 col-tiles of 32, both planes). B double-buffered in LDS (KCH=512,
// stage c+1 overlaps compute c). A streamed global->VGPR, no inner barriers.
// EPI=0: q8+ReLU -> hi/lo i8 planes. EPI=1: q8 fp32.
template <int EPI>
__global__ __launch_bounds__(512, 2) void gemm_i8_big(
    const uint8_t* __restrict__ Ah, const uint8_t* __restrict__ Al,
    const uint8_t* __restrict__ Bm,
    void* __restrict__ Ch, void* __restrict__ Cl,
    int M, int N, int K) {
    extern __shared__ uint8_t sB[];  // 2 buffers x 64 pairs x PSTR

    const int tid  = threadIdx.x;
    const int lane = tid & 63;
    const int wave = tid >> 6;     // 8 waves
    const int col  = lane & 31;    // col within 32-tile / A row within 32
    const int kh   = lane >> 5;    // k-half (16 B granule)
    const int bm = blockIdx.x, bn = blockIdx.y;

    v16i acc[2][4];
#pragma unroll
    for (int p = 0; p < 2; ++p)
#pragma unroll
        for (int j = 0; j < 4; ++j) acc[p][j] = (v16i)0;

    // A pointers: wave rows [wave*32, wave*32+32); lane covers row=col, khalf=kh
    const size_t arow = (size_t)(bm * 256 + wave * 32 + col);
    const uint8_t* pAh = Ah + arow * K + kh * 16;
    const uint8_t* pAl = Al + arow * K + kh * 16;

    // B staging geometry: wave w stages pairs p = w*8+c (rows 2p, 2p+1)
    const size_t brow = (size_t)(bn * 128 + wave * 16 + kh);  // kh selects row of pair
    // B frag read base (within buffer): tile j -> pair j*16 + col/2, half col&1
    int bbase[4];
#pragma unroll
    for (int j = 0; j < 4; ++j)
        bbase[j] = (j * 16 + (col >> 1)) * PSTR + (col & 1) * 512 + kh * 16;

    const int NC = K / KCH;
    // stage chunk 0 into buffer 0
    {
        const uint8_t* g = Bm + brow * K + (lane & 31) * 16;
        uint8_t* l = sB + wave * 8 * PSTR + lane * 16;
#pragma unroll
        for (int c = 0; c < 8; ++c)
            gl_lds16(g + (size_t)(2 * c) * K, l + c * PSTR);
    }

    for (int c = 0; c < NC; ++c) {
        __syncthreads();  // drains stage(c) (vmcnt(0) before s_barrier)
        if (c + 1 < NC) {  // stage next chunk into other buffer, overlapped
            const uint8_t* g = Bm + brow * K + (c + 1) * KCH + (lane & 31) * 16;
            uint8_t* l = sB + ((c + 1) & 1) * BUFB + wave * 8 * PSTR + lane * 16;
#pragma unroll
            for (int s = 0; s < 8; ++s)
                gl_lds16(g + (size_t)(2 * s) * K, l + s * PSTR);
        }
        const uint8_t* bufc = sB + (c & 1) * BUFB;
        const int kc = c * KCH;
#pragma unroll 4
        for (int k0 = 0; k0 < KCH; k0 += 32) {
            v4i a0 = *(const v4i*)(pAh + kc + k0);
            v4i a1 = *(const v4i*)(pAl + kc + k0);
            v4i b[4];
#pragma unroll
            for (int j = 0; j < 4; ++j)
                b[j] = *(const v4i*)(bufc + bbase[j] + k0);
#pragma unroll
            for (int j = 0; j < 4; ++j) {
                acc[0][j] = __builtin_amdgcn_mfma_i32_32x32x32_i8(a0, b[j], acc[0][j], 0, 0, 0);
                acc[1][j] = __builtin_amdgcn_mfma_i32_32x32x32_i8(a1, b[j], acc[1][j], 0, 0, 0);
            }
        }
    }

    // C/D layout (32x32): col = lane&31, row = (reg&3) + 8*(reg>>2) + 4*(lane>>5)
    const int cg0 = bn * 128 + col;
    const int rg0 = bm * 256 + wave * 32 + 4 * kh;
#pragma unroll
    for (int j = 0; j < 4; ++j) {
#pragma unroll
        for (int reg = 0; reg < 16; ++reg) {
            int mt = acc[0][j][reg] * 32 + acc[1][j][reg];  // exact, |mt| < 2^24
            size_t idx = (size_t)(rg0 + (reg & 3) + 8 * (reg >> 2)) * N
                       + (size_t)(cg0 + j * 32);
            if (EPI == 0) {
                // q8 (int RNE on 2^-18 grid) + ReLU -> h in 2^-9 units -> hi/lo
                uint8_t hb = 0, lb = 0;
                if (mt > 0) {
                    int s = 28 - __builtin_clz((uint32_t)mt);
                    if (s < 9) s = 9;
                    int mh = (int)(rne_sh((uint32_t)mt, s) << (s - 9));
                    hb = (uint8_t)(mh >> 5);
                    lb = (uint8_t)(mh & 31);
                }
                ((uint8_t*)Ch)[idx] = hb;
                ((uint8_t*)Cl)[idx] = lb;
            } else {
                uint32_t a = mt < 0 ? (uint32_t)(-mt) : (uint32_t)mt;
                float v = 0.0f;
                if (a) {
                    int s = 28 - __builtin_clz(a);
                    if (s < 9) s = 9;
                    v = (float)(rne_sh(a, s) << s) * 0x1p-18f;  // exact
                    if (mt < 0) v = -v;
                }
                ((float*)Ch)[idx] = v;
            }
        }
    }
}

extern "C" void kernel_launch(void* const* d_in, const int* in_sizes, int n_in,
                              void* d_out, int out_size, void* d_ws, size_t ws_size,
                              hipStream_t stream) {
    const int Bsz = 8192, DIN = 1024, DH = 4096, DOUT = 1024;
    const float* x  = (const float*)d_in[0];
    const float* w1 = (const float*)d_in[1];
    const float* w2 = (const float*)d_in[2];
    float* out = (float*)d_out;

    uint8_t* ws  = (uint8_t*)d_ws;
    uint8_t* xh  = ws;                            //  8 MB
    uint8_t* xl  = xh  + (size_t)Bsz * DIN;       //  8 MB
    uint8_t* w1m = xl  + (size_t)Bsz * DIN;       //  4 MB
    uint8_t* w2m = w1m + (size_t)DH  * DIN;       //  4 MB
    uint8_t* hh  = w2m + (size_t)DOUT * DH;       // 32 MB
    uint8_t* hl  = hh  + (size_t)Bsz * DH;        // 32 MB

    static bool attr_done = false;
    if (!attr_done) {
        hipFuncSetAttribute((const void*)gemm_i8_big<0>,
                            hipFuncAttributeMaxDynamicSharedMemorySize, LDSB);
        hipFuncSetAttribute((const void*)gemm_i8_big<1>,
                            hipFuncAttributeMaxDynamicSharedMemorySize, LDSB);
        attr_done = true;
    }

    quant_x_kernel<<<(Bsz * DIN / 4) / 256, 256, 0, stream>>>(
        x, (uint32_t*)xh, (uint32_t*)xl, Bsz * DIN / 4);
    quant_w_kernel<<<(DH * DIN / 4) / 256, 256, 0, stream>>>(
        w1, (uint32_t*)w1m, DH * DIN / 4);
    quant_w_kernel<<<(DOUT * DH / 4) / 256, 256, 0, stream>>>(
        w2, (uint32_t*)w2m, DOUT * DH / 4);

    // fc1: h = relu(q8(x8 @ w1q^T)) -> hi/lo  [8192,4096]
    dim3 g1(Bsz / 256, DH / 128);   // 32 x 32 = 1024 blocks
    gemm_i8_big<0><<<g1, 512, LDSB, stream>>>(xh, xl, w1m, (void*)hh, (void*)hl, Bsz, DH, DIN);

    // fc2: out = q8(h @ w2q^T)  [8192,1024] fp32
    dim3 g2(Bsz / 256, DOUT / 128); // 32 x 8 = 256 blocks
    gemm_i8_big<1><<<g2, 512, LDSB, stream>>>(hh, hl, w2m, (void*)out, nullptr, Bsz, DOUT, DH);
}